// Round 4
// baseline (516.583 us; speedup 1.0000x reference)
//
#include <hip/hip_runtime.h>
#include <math.h>

#define N_CELLS 100000
#define N_EDGES 1600000
#define FDIM 32
#define NEG_SLOPE 0.2f
#define NSEG (2 * N_CELLS)          // counts/offsets for both branches concatenated
#define SCAN_BLOCK 2048             // elements per scan block (256 thr x 8)
#define NSCAN_BLOCKS ((NSEG + SCAN_BLOCK - 1) / SCAN_BLOCK)   // 98
#define EDGE_BLOCKS ((2 * N_EDGES) / 256)                     // 12500 (exact)

__device__ __forceinline__ float leaky(float v) {
    return v > 0.f ? v : NEG_SLOPE * v;
}

// Kernel 1 (fused): h = x@W (both branches), per-node attention scores,
// AND src histogram. Grid: 12500 x 256 exactly covers 100000 rows (8/block)
// and 3.2M edge slots.
__global__ void k_fused(const float* __restrict__ x,
                        const float* __restrict__ Wirr, const float* __restrict__ Wsol,
                        const float* __restrict__ att_irr, const float* __restrict__ att_sol,
                        const int* __restrict__ do_idx, const int* __restrict__ up_idx,
                        float* __restrict__ h_irr, float* __restrict__ h_sol,
                        float* __restrict__ s_src_irr, float* __restrict__ s_tgt_irr,
                        float* __restrict__ s_src_sol, float* __restrict__ s_tgt_sol,
                        int* __restrict__ counts) {
    __shared__ float sWirr[FDIM * FDIM], sWsol[FDIM * FDIM];
    __shared__ float sAi[2 * FDIM], sAs[2 * FDIM];
    int t = threadIdx.x;
    for (int i = t; i < FDIM * FDIM; i += 256) { sWirr[i] = Wirr[i]; sWsol[i] = Wsol[i]; }
    if (t < 2 * FDIM) { sAi[t] = att_irr[t]; sAs[t] = att_sol[t]; }
    __syncthreads();

    // --- histogram of src for both branches ---
    int tid = blockIdx.x * 256 + t;
    if (tid < N_EDGES) atomicAdd(&counts[do_idx[tid]], 1);
    else atomicAdd(&counts[N_CELLS + up_idx[tid - N_EDGES]], 1);

    // --- h + scores: one wave handles 2 rows (32 lanes per row) ---
    int wave = t >> 6, lane = t & 63, halfsel = lane >> 5, f = lane & 31;
    int row = blockIdx.x * 8 + wave * 2 + halfsel;
    const float* xr = x + (size_t)row * FDIM;
    float hi = 0.f, hs = 0.f;
#pragma unroll
    for (int k = 0; k < FDIM; ++k) {
        float xv = xr[k];
        hi += xv * sWirr[k * FDIM + f];
        hs += xv * sWsol[k * FDIM + f];
    }
    h_irr[(size_t)row * FDIM + f] = hi;
    h_sol[(size_t)row * FDIM + f] = hs;

    float pi0 = hi * sAi[f], pi1 = hi * sAi[FDIM + f];
    float ps0 = hs * sAs[f], ps1 = hs * sAs[FDIM + f];
#pragma unroll
    for (int m = 16; m >= 1; m >>= 1) {
        pi0 += __shfl_xor(pi0, m);
        pi1 += __shfl_xor(pi1, m);
        ps0 += __shfl_xor(ps0, m);
        ps1 += __shfl_xor(ps1, m);
    }
    if (f == 0) {
        s_src_irr[row] = pi0;
        s_tgt_irr[row] = pi1;
        s_src_sol[row] = ps0;
        s_tgt_sol[row] = ps1;
    }
}

// Scan a: per-block exclusive scan of counts (2048 elems/block) + block sums.
__global__ void k_scan_a(const int* __restrict__ counts, int* __restrict__ offsets,
                         int* __restrict__ blksums) {
    __shared__ int sdata[256];
    int t = threadIdx.x;
    int base = blockIdx.x * SCAN_BLOCK + t * 8;
    int v[8];
    int sum = 0;
#pragma unroll
    for (int j = 0; j < 8; ++j) {
        v[j] = (base + j < NSEG) ? counts[base + j] : 0;
        sum += v[j];
    }
    sdata[t] = sum;
    __syncthreads();
    for (int off = 1; off < 256; off <<= 1) {
        int xv = (t >= off) ? sdata[t - off] : 0;
        __syncthreads();
        sdata[t] += xv;
        __syncthreads();
    }
    int excl = (t == 0) ? 0 : sdata[t - 1];
    if (t == 255) blksums[blockIdx.x] = sdata[255];
    int run = excl;
#pragma unroll
    for (int j = 0; j < 8; ++j) {
        if (base + j < NSEG) offsets[base + j] = run;
        run += v[j];
    }
}

// Scan b: exclusive scan of the block sums (single block).
__global__ void k_scan_b(int* __restrict__ blksums) {
    __shared__ int s[128];
    int t = threadIdx.x;
    s[t] = (t < NSCAN_BLOCKS) ? blksums[t] : 0;
    __syncthreads();
    for (int off = 1; off < 128; off <<= 1) {
        int xv = (t >= off) ? s[t - off] : 0;
        __syncthreads();
        s[t] += xv;
        __syncthreads();
    }
    if (t < NSCAN_BLOCKS) blksums[t] = (t == 0) ? 0 : s[t - 1];
}

// Scan c: add block offsets; also copy into cursor.
__global__ void k_scan_c(int* __restrict__ offsets, int* __restrict__ cursor,
                         const int* __restrict__ blksums) {
    int i = blockIdx.x * 256 + threadIdx.x;
    if (i < NSEG) {
        int vv = offsets[i] + blksums[i >> 11];
        offsets[i] = vv;
        cursor[i] = vv;
    }
}

// Scatter: build CSR target lists.
__global__ void k_scatter(const int* __restrict__ do_idx, const int* __restrict__ up_idx,
                          int* __restrict__ cursor, int* __restrict__ csr_tgt) {
    int tid = blockIdx.x * 256 + threadIdx.x;          // exact grid: 2*N_EDGES
    if (tid < N_EDGES) {
        int s = do_idx[tid], t = do_idx[N_EDGES + tid];
        int pos = atomicAdd(&cursor[s], 1);
        csr_tgt[pos] = t;
    } else {
        int e = tid - N_EDGES;
        int s = up_idx[e], t = up_idx[N_EDGES + e];
        int pos = atomicAdd(&cursor[N_CELLS + s], 1);
        csr_tgt[pos] = t;
    }
}

// Per-branch accumulation with WAVE-UNIFORM control flow.
// Phase A: lane i holds edge i's (target, score); exact online max per chunk.
// Phase B: uniform loops; half-selection via shuffle SOURCE index (i+2j+half),
// so every __shfl executes with all 64 lanes active. Tail pairs clamp the
// source lane and zero the weight (predication, never divergent shuffles).
__device__ __forceinline__ float branch_acc(int seg, int n, int lane, int f, int half,
                                            const int* __restrict__ csr_tgt,
                                            const int* __restrict__ offsets,
                                            const int* __restrict__ counts,
                                            const float* __restrict__ s_src,
                                            const float* __restrict__ s_tgt,
                                            const float* __restrict__ h) {
    int beg = offsets[seg];
    int deg = counts[seg];
    float ssrc = s_src[n];
    float num = 0.f, den = 0.f, Mrun = -INFINITY;
    for (int base = 0; base < deg; base += 64) {
        int m = deg - base;
        if (m > 64) m = 64;
        int te = 0;
        float ev = -INFINITY;
        if (lane < m) {
            te = csr_tgt[beg + base + lane];
            ev = leaky(ssrc + s_tgt[te]);
        }
        // exact chunk max (allreduce over the wave)
        float cm = ev;
#pragma unroll
        for (int d = 32; d >= 1; d >>= 1) cm = fmaxf(cm, __shfl_xor(cm, d));
        float newM = fmaxf(Mrun, cm);
        float scale = __expf(Mrun - newM);   // 0 on first chunk (num=den=0)
        num *= scale;
        den *= scale;
        Mrun = newM;
        float we = __expf(ev - newM);        // 0 for lanes >= m (ev = -inf)

        int i = 0;
        for (; i + 15 < m; i += 16) {        // 8 independent gathers per lane
            int  t0 = __shfl(te, i +  0 + half), t1 = __shfl(te, i +  2 + half);
            int  t2 = __shfl(te, i +  4 + half), t3 = __shfl(te, i +  6 + half);
            int  t4 = __shfl(te, i +  8 + half), t5 = __shfl(te, i + 10 + half);
            int  t6 = __shfl(te, i + 12 + half), t7 = __shfl(te, i + 14 + half);
            float w0 = __shfl(we, i +  0 + half), w1 = __shfl(we, i +  2 + half);
            float w2 = __shfl(we, i +  4 + half), w3 = __shfl(we, i +  6 + half);
            float w4 = __shfl(we, i +  8 + half), w5 = __shfl(we, i + 10 + half);
            float w6 = __shfl(we, i + 12 + half), w7 = __shfl(we, i + 14 + half);
            float v0 = h[(size_t)t0 * FDIM + f], v1 = h[(size_t)t1 * FDIM + f];
            float v2 = h[(size_t)t2 * FDIM + f], v3 = h[(size_t)t3 * FDIM + f];
            float v4 = h[(size_t)t4 * FDIM + f], v5 = h[(size_t)t5 * FDIM + f];
            float v6 = h[(size_t)t6 * FDIM + f], v7 = h[(size_t)t7 * FDIM + f];
            num += w0 * v0 + w1 * v1 + w2 * v2 + w3 * v3;
            num += w4 * v4 + w5 * v5 + w6 * v6 + w7 * v7;
            den += w0 + w1 + w2 + w3 + w4 + w5 + w6 + w7;
        }
        for (; i + 7 < m; i += 8) {          // 4 independent gathers per lane
            int  t0 = __shfl(te, i + 0 + half), t1 = __shfl(te, i + 2 + half);
            int  t2 = __shfl(te, i + 4 + half), t3 = __shfl(te, i + 6 + half);
            float w0 = __shfl(we, i + 0 + half), w1 = __shfl(we, i + 2 + half);
            float w2 = __shfl(we, i + 4 + half), w3 = __shfl(we, i + 6 + half);
            float v0 = h[(size_t)t0 * FDIM + f], v1 = h[(size_t)t1 * FDIM + f];
            float v2 = h[(size_t)t2 * FDIM + f], v3 = h[(size_t)t3 * FDIM + f];
            num += w0 * v0 + w1 * v1 + w2 * v2 + w3 * v3;
            den += w0 + w1 + w2 + w3;
        }
        for (; i < m; i += 2) {              // uniform pair tail, clamped source
            int idx = i + half;
            int safe = (idx < m) ? idx : i;
            int tt = __shfl(te, safe);
            float ww = __shfl(we, safe);
            ww = (idx < m) ? ww : 0.f;
            num += ww * h[(size_t)tt * FDIM + f];
            den += ww;
        }
    }
    num += __shfl_xor(num, 32);
    den += __shfl_xor(den, 32);
    return num / (den + 1e-10f);
}

// Final aggregate: one 64-lane wave per node; ELU fused; single out write.
__global__ void k_node_aggregate(const int* __restrict__ csr_tgt,
                                 const int* __restrict__ offsets, const int* __restrict__ counts,
                                 const float* __restrict__ s_src_irr, const float* __restrict__ s_tgt_irr,
                                 const float* __restrict__ s_src_sol, const float* __restrict__ s_tgt_sol,
                                 const float* __restrict__ h_irr, const float* __restrict__ h_sol,
                                 float* __restrict__ out) {
    int wave = threadIdx.x >> 6;
    int lane = threadIdx.x & 63;
    int n = blockIdx.x * 4 + wave;     // grid 25000 exact
    int f = lane & 31;
    int half = lane >> 5;

    float res = branch_acc(n, n, lane, f, half, csr_tgt, offsets, counts,
                           s_src_irr, s_tgt_irr, h_irr);
    res += branch_acc(N_CELLS + n, n, lane, f, half, csr_tgt, offsets, counts,
                      s_src_sol, s_tgt_sol, h_sol);
    res = res > 0.f ? res : __expf(res) - 1.f;   // ELU
    if (half == 0) out[(size_t)n * FDIM + f] = res;
}

extern "C" void kernel_launch(void* const* d_in, const int* in_sizes, int n_in,
                              void* d_out, int out_size, void* d_ws, size_t ws_size,
                              hipStream_t stream) {
    const float* x = (const float*)d_in[0];
    const int* do_index = (const int*)d_in[1];
    const int* up_index = (const int*)d_in[2];
    const float* Wirr = (const float*)d_in[3];
    const float* Wsol = (const float*)d_in[4];
    const float* att_irr = (const float*)d_in[5];
    const float* att_sol = (const float*)d_in[6];
    float* out = (float*)d_out;

    // Workspace partition
    float* ws = (float*)d_ws;
    float* h_irr = ws;                                   // N*F
    float* h_sol = h_irr + (size_t)N_CELLS * FDIM;       // N*F
    float* s_src_irr = h_sol + (size_t)N_CELLS * FDIM;   // N
    float* s_tgt_irr = s_src_irr + N_CELLS;              // N
    float* s_src_sol = s_tgt_irr + N_CELLS;              // N
    float* s_tgt_sol = s_src_sol + N_CELLS;              // N
    int* counts = (int*)(s_tgt_sol + N_CELLS);           // NSEG
    int* offsets = counts + NSEG;                        // NSEG
    int* cursor = offsets + NSEG;                        // NSEG
    int* blksums = cursor + NSEG;                        // 128
    int* csr_tgt = blksums + 128;                        // 2*N_EDGES

    hipMemsetAsync(counts, 0, NSEG * sizeof(int), stream);

    // K1: fused h + scores + histogram
    hipLaunchKernelGGL(k_fused, dim3(EDGE_BLOCKS), dim3(256), 0, stream,
                       x, Wirr, Wsol, att_irr, att_sol, do_index, up_index,
                       h_irr, h_sol, s_src_irr, s_tgt_irr, s_src_sol, s_tgt_sol,
                       counts);

    // K2: exclusive scan of counts -> offsets (+cursor copy)
    hipLaunchKernelGGL(k_scan_a, dim3(NSCAN_BLOCKS), dim3(256), 0, stream,
                       counts, offsets, blksums);
    hipLaunchKernelGGL(k_scan_b, dim3(1), dim3(128), 0, stream, blksums);
    hipLaunchKernelGGL(k_scan_c, dim3((NSEG + 255) / 256), dim3(256), 0, stream,
                       offsets, cursor, blksums);

    // K3: scatter into CSR
    hipLaunchKernelGGL(k_scatter, dim3(EDGE_BLOCKS), dim3(256), 0, stream,
                       do_index, up_index, cursor, csr_tgt);

    // K4: per-node aggregate + ELU (1 wave/node, 4 waves/block -> exact grid)
    hipLaunchKernelGGL(k_node_aggregate, dim3(N_CELLS / 4), dim3(256), 0, stream,
                       csr_tgt, offsets, counts,
                       s_src_irr, s_tgt_irr, s_src_sol, s_tgt_sol,
                       h_irr, h_sol, out);
}

// Round 5
// 399.221 us; speedup vs baseline: 1.2940x; 1.2940x over previous
//
#include <hip/hip_runtime.h>
#include <math.h>

#define N_CELLS 100000
#define N_EDGES 1600000
#define FDIM 32
#define NEG_SLOPE 0.2f
#define NSEG (2 * N_CELLS)          // counts/offsets for both branches concatenated
#define SCAN_BLOCK 2048             // elements per scan block (256 thr x 8)
#define NSCAN_BLOCKS ((NSEG + SCAN_BLOCK - 1) / SCAN_BLOCK)   // 98
#define EDGE_BLOCKS ((2 * N_EDGES) / 256)                     // 12500 (exact)
#define RANGE_DIV (NSEG / 8)        // 25000 segments per XCD-range

__device__ __forceinline__ float leaky(float v) {
    return v > 0.f ? v : NEG_SLOPE * v;
}

// Kernel 1 (fused): h = x@W (both branches), per-node attention scores,
// AND src histogram. Grid: 12500 x 256 exactly covers 100000 rows (8/block)
// and 3.2M edge slots.
__global__ void k_fused(const float* __restrict__ x,
                        const float* __restrict__ Wirr, const float* __restrict__ Wsol,
                        const float* __restrict__ att_irr, const float* __restrict__ att_sol,
                        const int* __restrict__ do_idx, const int* __restrict__ up_idx,
                        float* __restrict__ h_irr, float* __restrict__ h_sol,
                        float* __restrict__ s_src_irr, float* __restrict__ s_tgt_irr,
                        float* __restrict__ s_src_sol, float* __restrict__ s_tgt_sol,
                        int* __restrict__ counts) {
    __shared__ float sWirr[FDIM * FDIM], sWsol[FDIM * FDIM];
    __shared__ float sAi[2 * FDIM], sAs[2 * FDIM];
    int t = threadIdx.x;
    for (int i = t; i < FDIM * FDIM; i += 256) { sWirr[i] = Wirr[i]; sWsol[i] = Wsol[i]; }
    if (t < 2 * FDIM) { sAi[t] = att_irr[t]; sAs[t] = att_sol[t]; }
    __syncthreads();

    // --- histogram of src for both branches ---
    int tid = blockIdx.x * 256 + t;
    if (tid < N_EDGES) atomicAdd(&counts[do_idx[tid]], 1);
    else atomicAdd(&counts[N_CELLS + up_idx[tid - N_EDGES]], 1);

    // --- h + scores: one wave handles 2 rows (32 lanes per row) ---
    int wave = t >> 6, lane = t & 63, halfsel = lane >> 5, f = lane & 31;
    int row = blockIdx.x * 8 + wave * 2 + halfsel;
    const float* xr = x + (size_t)row * FDIM;
    float hi = 0.f, hs = 0.f;
#pragma unroll
    for (int k = 0; k < FDIM; ++k) {
        float xv = xr[k];
        hi += xv * sWirr[k * FDIM + f];
        hs += xv * sWsol[k * FDIM + f];
    }
    h_irr[(size_t)row * FDIM + f] = hi;
    h_sol[(size_t)row * FDIM + f] = hs;

    float pi0 = hi * sAi[f], pi1 = hi * sAi[FDIM + f];
    float ps0 = hs * sAs[f], ps1 = hs * sAs[FDIM + f];
#pragma unroll
    for (int m = 16; m >= 1; m >>= 1) {
        pi0 += __shfl_xor(pi0, m);
        pi1 += __shfl_xor(pi1, m);
        ps0 += __shfl_xor(ps0, m);
        ps1 += __shfl_xor(ps1, m);
    }
    if (f == 0) {
        s_src_irr[row] = pi0;
        s_tgt_irr[row] = pi1;
        s_src_sol[row] = ps0;
        s_tgt_sol[row] = ps1;
    }
}

// Scan a: per-block exclusive scan of counts (2048 elems/block) + block sums.
__global__ void k_scan_a(const int* __restrict__ counts, int* __restrict__ offsets,
                         int* __restrict__ blksums) {
    __shared__ int sdata[256];
    int t = threadIdx.x;
    int base = blockIdx.x * SCAN_BLOCK + t * 8;
    int v[8];
    int sum = 0;
#pragma unroll
    for (int j = 0; j < 8; ++j) {
        v[j] = (base + j < NSEG) ? counts[base + j] : 0;
        sum += v[j];
    }
    sdata[t] = sum;
    __syncthreads();
    for (int off = 1; off < 256; off <<= 1) {
        int xv = (t >= off) ? sdata[t - off] : 0;
        __syncthreads();
        sdata[t] += xv;
        __syncthreads();
    }
    int excl = (t == 0) ? 0 : sdata[t - 1];
    if (t == 255) blksums[blockIdx.x] = sdata[255];
    int run = excl;
#pragma unroll
    for (int j = 0; j < 8; ++j) {
        if (base + j < NSEG) offsets[base + j] = run;
        run += v[j];
    }
}

// Scan b: exclusive scan of the block sums (single block).
__global__ void k_scan_b(int* __restrict__ blksums) {
    __shared__ int s[128];
    int t = threadIdx.x;
    s[t] = (t < NSCAN_BLOCKS) ? blksums[t] : 0;
    __syncthreads();
    for (int off = 1; off < 128; off <<= 1) {
        int xv = (t >= off) ? s[t - off] : 0;
        __syncthreads();
        s[t] += xv;
        __syncthreads();
    }
    if (t < NSCAN_BLOCKS) blksums[t] = (t == 0) ? 0 : s[t - 1];
}

// Scan c: add block offsets; also copy into cursor.
__global__ void k_scan_c(int* __restrict__ offsets, int* __restrict__ cursor,
                         const int* __restrict__ blksums) {
    int i = blockIdx.x * 256 + threadIdx.x;
    if (i < NSEG) {
        int vv = offsets[i] + blksums[i >> 11];
        offsets[i] = vv;
        cursor[i] = vv;
    }
}

// Scatter: build CSR target lists, XCD-range partitioned.
// Grid = 8 * EDGE_BLOCKS. Block b handles edge chunk (b>>3) and only scatters
// segments in range r = b&7 (25000 segs -> 100KB cursor + 1.6MB CSR slice,
// which fits in one XCD's 4MB L2). With round-robin block->XCD dispatch each
// range's writes stay in a single L2: lines coalesce and write back once.
// The 8 blocks sharing a chunk are consecutive -> concurrent -> L3 absorbs
// the 8x edge re-read. Correct regardless of actual block->XCD mapping.
__global__ void k_scatter(const int* __restrict__ do_idx, const int* __restrict__ up_idx,
                          int* __restrict__ cursor, int* __restrict__ csr_tgt) {
    int r = blockIdx.x & 7;
    int chunk = blockIdx.x >> 3;
    int tid = chunk * 256 + threadIdx.x;               // chunk covers one branch only
    int seg, t;
    if (tid < N_EDGES) {
        seg = do_idx[tid];
        t = do_idx[N_EDGES + tid];
    } else {
        int e = tid - N_EDGES;
        seg = N_CELLS + up_idx[e];
        t = up_idx[N_EDGES + e];
    }
    if (seg / RANGE_DIV == r) {
        int pos = atomicAdd(&cursor[seg], 1);
        csr_tgt[pos] = t;
    }
}

// Per-branch accumulation with WAVE-UNIFORM control flow.
// Phase A: lane i holds edge i's (target, score); exact online max per chunk.
// Phase B: uniform loops; half-selection via shuffle SOURCE index (i+2j+half),
// so every __shfl executes with all 64 lanes active. Tail pairs clamp the
// source lane and zero the weight (predication, never divergent shuffles).
__device__ __forceinline__ float branch_acc(int seg, int n, int lane, int f, int half,
                                            const int* __restrict__ csr_tgt,
                                            const int* __restrict__ offsets,
                                            const int* __restrict__ counts,
                                            const float* __restrict__ s_src,
                                            const float* __restrict__ s_tgt,
                                            const float* __restrict__ h) {
    int beg = offsets[seg];
    int deg = counts[seg];
    float ssrc = s_src[n];
    float num = 0.f, den = 0.f, Mrun = -INFINITY;
    for (int base = 0; base < deg; base += 64) {
        int m = deg - base;
        if (m > 64) m = 64;
        int te = 0;
        float ev = -INFINITY;
        if (lane < m) {
            te = csr_tgt[beg + base + lane];
            ev = leaky(ssrc + s_tgt[te]);
        }
        // exact chunk max (allreduce over the wave)
        float cm = ev;
#pragma unroll
        for (int d = 32; d >= 1; d >>= 1) cm = fmaxf(cm, __shfl_xor(cm, d));
        float newM = fmaxf(Mrun, cm);
        float scale = __expf(Mrun - newM);   // 0 on first chunk (num=den=0)
        num *= scale;
        den *= scale;
        Mrun = newM;
        float we = __expf(ev - newM);        // 0 for lanes >= m (ev = -inf)

        int i = 0;
        for (; i + 15 < m; i += 16) {        // 8 independent gathers per lane
            int  t0 = __shfl(te, i +  0 + half), t1 = __shfl(te, i +  2 + half);
            int  t2 = __shfl(te, i +  4 + half), t3 = __shfl(te, i +  6 + half);
            int  t4 = __shfl(te, i +  8 + half), t5 = __shfl(te, i + 10 + half);
            int  t6 = __shfl(te, i + 12 + half), t7 = __shfl(te, i + 14 + half);
            float w0 = __shfl(we, i +  0 + half), w1 = __shfl(we, i +  2 + half);
            float w2 = __shfl(we, i +  4 + half), w3 = __shfl(we, i +  6 + half);
            float w4 = __shfl(we, i +  8 + half), w5 = __shfl(we, i + 10 + half);
            float w6 = __shfl(we, i + 12 + half), w7 = __shfl(we, i + 14 + half);
            float v0 = h[(size_t)t0 * FDIM + f], v1 = h[(size_t)t1 * FDIM + f];
            float v2 = h[(size_t)t2 * FDIM + f], v3 = h[(size_t)t3 * FDIM + f];
            float v4 = h[(size_t)t4 * FDIM + f], v5 = h[(size_t)t5 * FDIM + f];
            float v6 = h[(size_t)t6 * FDIM + f], v7 = h[(size_t)t7 * FDIM + f];
            num += w0 * v0 + w1 * v1 + w2 * v2 + w3 * v3;
            num += w4 * v4 + w5 * v5 + w6 * v6 + w7 * v7;
            den += w0 + w1 + w2 + w3 + w4 + w5 + w6 + w7;
        }
        for (; i + 7 < m; i += 8) {          // 4 independent gathers per lane
            int  t0 = __shfl(te, i + 0 + half), t1 = __shfl(te, i + 2 + half);
            int  t2 = __shfl(te, i + 4 + half), t3 = __shfl(te, i + 6 + half);
            float w0 = __shfl(we, i + 0 + half), w1 = __shfl(we, i + 2 + half);
            float w2 = __shfl(we, i + 4 + half), w3 = __shfl(we, i + 6 + half);
            float v0 = h[(size_t)t0 * FDIM + f], v1 = h[(size_t)t1 * FDIM + f];
            float v2 = h[(size_t)t2 * FDIM + f], v3 = h[(size_t)t3 * FDIM + f];
            num += w0 * v0 + w1 * v1 + w2 * v2 + w3 * v3;
            den += w0 + w1 + w2 + w3;
        }
        for (; i < m; i += 2) {              // uniform pair tail, clamped source
            int idx = i + half;
            int safe = (idx < m) ? idx : i;
            int tt = __shfl(te, safe);
            float ww = __shfl(we, safe);
            ww = (idx < m) ? ww : 0.f;
            num += ww * h[(size_t)tt * FDIM + f];
            den += ww;
        }
    }
    num += __shfl_xor(num, 32);
    den += __shfl_xor(den, 32);
    return num / (den + 1e-10f);
}

// Final aggregate: one 64-lane wave per node; ELU fused; single out write.
__global__ void k_node_aggregate(const int* __restrict__ csr_tgt,
                                 const int* __restrict__ offsets, const int* __restrict__ counts,
                                 const float* __restrict__ s_src_irr, const float* __restrict__ s_tgt_irr,
                                 const float* __restrict__ s_src_sol, const float* __restrict__ s_tgt_sol,
                                 const float* __restrict__ h_irr, const float* __restrict__ h_sol,
                                 float* __restrict__ out) {
    int wave = threadIdx.x >> 6;
    int lane = threadIdx.x & 63;
    int n = blockIdx.x * 4 + wave;     // grid 25000 exact
    int f = lane & 31;
    int half = lane >> 5;

    float res = branch_acc(n, n, lane, f, half, csr_tgt, offsets, counts,
                           s_src_irr, s_tgt_irr, h_irr);
    res += branch_acc(N_CELLS + n, n, lane, f, half, csr_tgt, offsets, counts,
                      s_src_sol, s_tgt_sol, h_sol);
    res = res > 0.f ? res : __expf(res) - 1.f;   // ELU
    if (half == 0) out[(size_t)n * FDIM + f] = res;
}

extern "C" void kernel_launch(void* const* d_in, const int* in_sizes, int n_in,
                              void* d_out, int out_size, void* d_ws, size_t ws_size,
                              hipStream_t stream) {
    const float* x = (const float*)d_in[0];
    const int* do_index = (const int*)d_in[1];
    const int* up_index = (const int*)d_in[2];
    const float* Wirr = (const float*)d_in[3];
    const float* Wsol = (const float*)d_in[4];
    const float* att_irr = (const float*)d_in[5];
    const float* att_sol = (const float*)d_in[6];
    float* out = (float*)d_out;

    // Workspace partition
    float* ws = (float*)d_ws;
    float* h_irr = ws;                                   // N*F
    float* h_sol = h_irr + (size_t)N_CELLS * FDIM;       // N*F
    float* s_src_irr = h_sol + (size_t)N_CELLS * FDIM;   // N
    float* s_tgt_irr = s_src_irr + N_CELLS;              // N
    float* s_src_sol = s_tgt_irr + N_CELLS;              // N
    float* s_tgt_sol = s_src_sol + N_CELLS;              // N
    int* counts = (int*)(s_tgt_sol + N_CELLS);           // NSEG
    int* offsets = counts + NSEG;                        // NSEG
    int* cursor = offsets + NSEG;                        // NSEG
    int* blksums = cursor + NSEG;                        // 128
    int* csr_tgt = blksums + 128;                        // 2*N_EDGES

    hipMemsetAsync(counts, 0, NSEG * sizeof(int), stream);

    // K1: fused h + scores + histogram
    hipLaunchKernelGGL(k_fused, dim3(EDGE_BLOCKS), dim3(256), 0, stream,
                       x, Wirr, Wsol, att_irr, att_sol, do_index, up_index,
                       h_irr, h_sol, s_src_irr, s_tgt_irr, s_src_sol, s_tgt_sol,
                       counts);

    // K2: exclusive scan of counts -> offsets (+cursor copy)
    hipLaunchKernelGGL(k_scan_a, dim3(NSCAN_BLOCKS), dim3(256), 0, stream,
                       counts, offsets, blksums);
    hipLaunchKernelGGL(k_scan_b, dim3(1), dim3(128), 0, stream, blksums);
    hipLaunchKernelGGL(k_scan_c, dim3((NSEG + 255) / 256), dim3(256), 0, stream,
                       offsets, cursor, blksums);

    // K3: scatter into CSR (XCD-range partitioned, 8x filtered re-read)
    hipLaunchKernelGGL(k_scatter, dim3(8 * EDGE_BLOCKS), dim3(256), 0, stream,
                       do_index, up_index, cursor, csr_tgt);

    // K4: per-node aggregate + ELU (1 wave/node, 4 waves/block -> exact grid)
    hipLaunchKernelGGL(k_node_aggregate, dim3(N_CELLS / 4), dim3(256), 0, stream,
                       csr_tgt, offsets, counts,
                       s_src_irr, s_tgt_irr, s_src_sol, s_tgt_sol,
                       h_irr, h_sol, out);
}